// Round 1
// baseline (359.199 us; speedup 1.0000x reference)
//
#include <hip/hip_runtime.h>

#define D 128

// ---------------- CSR build ----------------

__global__ void count_deg_kernel(const int* __restrict__ dst, int* __restrict__ cnt, int E) {
    int e = blockIdx.x * 256 + threadIdx.x;
    if (e < E) atomicAdd(&cnt[dst[e]], 1);
}

__global__ void scan1_kernel(const int* __restrict__ cnt, int* __restrict__ rowptr,
                             int* __restrict__ bsum, int N) {
    __shared__ int tmp[256];
    int tid = threadIdx.x;
    int i = blockIdx.x * 256 + tid;
    int v = (i < N) ? cnt[i] : 0;
    tmp[tid] = v;
    __syncthreads();
    for (int off = 1; off < 256; off <<= 1) {
        int t = (tid >= off) ? tmp[tid - off] : 0;
        __syncthreads();
        tmp[tid] += t;
        __syncthreads();
    }
    if (i < N) rowptr[i] = tmp[tid] - v;            // exclusive within block
    if (tid == 255) bsum[blockIdx.x] = tmp[255];    // block total
}

__global__ void scan2_kernel(int* __restrict__ bsum, int NB) {
    __shared__ int tmp[256];
    int tid = threadIdx.x;
    int v = (tid < NB) ? bsum[tid] : 0;
    tmp[tid] = v;
    __syncthreads();
    for (int off = 1; off < 256; off <<= 1) {
        int t = (tid >= off) ? tmp[tid - off] : 0;
        __syncthreads();
        tmp[tid] += t;
        __syncthreads();
    }
    if (tid < NB) bsum[tid] = tmp[tid] - v;         // exclusive block offsets
}

__global__ void scan3_kernel(int* __restrict__ rowptr, const int* __restrict__ bsum,
                             int* __restrict__ cursor, int N, int E) {
    int i = blockIdx.x * 256 + threadIdx.x;
    if (i < N) {
        int v = rowptr[i] + bsum[blockIdx.x];
        rowptr[i] = v;
        cursor[i] = v;
    }
    if (i == 0) rowptr[N] = E;
}

__global__ void fill_kernel(const int* __restrict__ src, const int* __restrict__ dst,
                            int* __restrict__ cursor, int* __restrict__ ssrc, int E) {
    int e = blockIdx.x * 256 + threadIdx.x;
    if (e < E) {
        int d = dst[e];
        int pos = atomicAdd(&cursor[d], 1);
        ssrc[pos] = src[e];
    }
}

// ---------------- mean aggregation: one wave per destination node ----------------

__global__ void agg_kernel(const float* __restrict__ feat, const int* __restrict__ rowptr,
                           const int* __restrict__ ssrc, float* __restrict__ out, int N) {
    int w = (blockIdx.x * blockDim.x + threadIdx.x) >> 6;   // node id
    int lane = threadIdx.x & 63;
    if (w >= N) return;
    int beg = rowptr[w], end = rowptr[w + 1];
    float ax = 0.f, ay = 0.f;
    for (int e = beg; e < end; ++e) {
        int s = ssrc[e];
        const float2 v = *reinterpret_cast<const float2*>(feat + (size_t)s * D + lane * 2);
        ax += v.x;
        ay += v.y;
    }
    int deg = end - beg;
    float inv = 1.0f / (float)(deg > 1 ? deg : 1);
    float2 r;
    r.x = ax * inv;
    r.y = ay * inv;
    *reinterpret_cast<float2*>(out + (size_t)w * D + lane * 2) = r;
}

// ---------------- fused dual-GEMM: out = A1*W1 + A2*W2 + bias [, relu] ----------------
// Block tile: 128 rows x 128 cols, per-thread 8x8, BK = 32, two K=128 passes.

template <bool RELU>
__global__ __launch_bounds__(256)
void gemm2_kernel(const float* __restrict__ A1, const float* __restrict__ A2,
                  const float* __restrict__ W1, const float* __restrict__ W2,
                  const float* __restrict__ bias, float* __restrict__ out, int N) {
    __shared__ float At[32][132];   // A chunk, transposed, +4 pad (keeps 16B align, breaks conflicts)
    __shared__ float Wt[32][128];   // W chunk as-is

    int tid = threadIdx.x;
    int tx = tid & 15;          // column group 0..15 -> cols tx*8 .. tx*8+7
    int ty = tid >> 4;          // row group    0..15 -> rows ty*8 .. ty*8+7
    int row0 = blockIdx.x * 128;

    float acc[8][8];
#pragma unroll
    for (int i = 0; i < 8; ++i)
#pragma unroll
        for (int j = 0; j < 8; ++j) acc[i][j] = 0.f;

    float bb[8];
#pragma unroll
    for (int j = 0; j < 8; ++j) bb[j] = bias[tx * 8 + j];

#pragma unroll
    for (int pass = 0; pass < 2; ++pass) {
        const float* __restrict__ A = pass ? A2 : A1;
        const float* __restrict__ W = pass ? W2 : W1;
        for (int k0 = 0; k0 < 128; k0 += 32) {
            // stage A chunk (128 rows x 32 k) transposed into At
            {
                int kk = (tid & 7) * 4;
#pragma unroll
                for (int i = 0; i < 4; ++i) {
                    int rl = (tid >> 3) + i * 32;
                    int r = row0 + rl;
                    float4 v = make_float4(0.f, 0.f, 0.f, 0.f);
                    if (r < N)
                        v = *reinterpret_cast<const float4*>(A + (size_t)r * D + k0 + kk);
                    At[kk + 0][rl] = v.x;
                    At[kk + 1][rl] = v.y;
                    At[kk + 2][rl] = v.z;
                    At[kk + 3][rl] = v.w;
                }
            }
            // stage W chunk (32 k x 128 cols)
            {
#pragma unroll
                for (int i = 0; i < 4; ++i) {
                    int idx = tid + i * 256;   // float4 index 0..1023
                    int kr = idx >> 5;         // 32 float4 per k-row
                    int c4 = idx & 31;
                    float4 v = *reinterpret_cast<const float4*>(W + (size_t)(k0 + kr) * D + c4 * 4);
                    *reinterpret_cast<float4*>(&Wt[kr][c4 * 4]) = v;
                }
            }
            __syncthreads();
#pragma unroll
            for (int kk = 0; kk < 32; ++kk) {
                float a[8], w[8];
                *reinterpret_cast<float4*>(&a[0]) = *reinterpret_cast<const float4*>(&At[kk][ty * 8]);
                *reinterpret_cast<float4*>(&a[4]) = *reinterpret_cast<const float4*>(&At[kk][ty * 8 + 4]);
                *reinterpret_cast<float4*>(&w[0]) = *reinterpret_cast<const float4*>(&Wt[kk][tx * 8]);
                *reinterpret_cast<float4*>(&w[4]) = *reinterpret_cast<const float4*>(&Wt[kk][tx * 8 + 4]);
#pragma unroll
                for (int i = 0; i < 8; ++i)
#pragma unroll
                    for (int j = 0; j < 8; ++j) acc[i][j] += a[i] * w[j];
            }
            __syncthreads();
        }
    }

    // epilogue
#pragma unroll
    for (int i = 0; i < 8; ++i) {
        int r = row0 + ty * 8 + i;
        if (r >= N) continue;
#pragma unroll
        for (int j = 0; j < 8; j += 4) {
            float4 v;
            v.x = acc[i][j + 0] + bb[j + 0];
            v.y = acc[i][j + 1] + bb[j + 1];
            v.z = acc[i][j + 2] + bb[j + 2];
            v.w = acc[i][j + 3] + bb[j + 3];
            if (RELU) {
                v.x = v.x > 0.f ? v.x : 0.f;
                v.y = v.y > 0.f ? v.y : 0.f;
                v.z = v.z > 0.f ? v.z : 0.f;
                v.w = v.w > 0.f ? v.w : 0.f;
            }
            *reinterpret_cast<float4*>(out + (size_t)r * D + tx * 8 + j) = v;
        }
    }
}

// ---------------- launch ----------------

extern "C" void kernel_launch(void* const* d_in, const int* in_sizes, int n_in,
                              void* d_out, int out_size, void* d_ws, size_t ws_size,
                              hipStream_t stream) {
    const float* x    = (const float*)d_in[0];
    const int*   eidx = (const int*)d_in[1];
    const float* W_l1 = (const float*)d_in[2];
    const float* W_r1 = (const float*)d_in[3];
    const float* b1   = (const float*)d_in[4];
    const float* W_l2 = (const float*)d_in[5];
    const float* W_r2 = (const float*)d_in[6];
    const float* b2   = (const float*)d_in[7];
    float* out = (float*)d_out;

    const int N = in_sizes[0] / D;
    const int E = in_sizes[1] / 2;
    const int* src = eidx;
    const int* dst = eidx + E;

    // workspace bump allocator (512B aligned)
    char* ws = (char*)d_ws;
    size_t off = 0;
    auto alloc = [&](size_t bytes) {
        char* p = ws + off;
        off += (bytes + 511) & ~(size_t)511;
        return p;
    };
    int*   cnt      = (int*)alloc((size_t)N * 4);
    int*   rowptr   = (int*)alloc((size_t)(N + 1) * 4);
    int*   cursor   = (int*)alloc((size_t)N * 4);
    int*   bsum     = (int*)alloc(1024);
    int*   ssrc     = (int*)alloc((size_t)E * 4);
    float* aggn     = (float*)alloc((size_t)N * D * 4);
    float* h        = (float*)alloc((size_t)N * D * 4);

    const int NB_edges = (E + 255) / 256;
    const int NB_nodes = (N + 255) / 256;   // scan blocks (<= 256 required)
    const int NB_agg   = (N + 3) / 4;       // 4 waves/block, 1 node/wave
    const int NB_gemm  = (N + 127) / 128;

    // ---- CSR build (shared by both layers) ----
    hipMemsetAsync(cnt, 0, (size_t)N * 4, stream);
    count_deg_kernel<<<NB_edges, 256, 0, stream>>>(dst, cnt, E);
    scan1_kernel<<<NB_nodes, 256, 0, stream>>>(cnt, rowptr, bsum, N);
    scan2_kernel<<<1, 256, 0, stream>>>(bsum, NB_nodes);
    scan3_kernel<<<NB_nodes, 256, 0, stream>>>(rowptr, bsum, cursor, N, E);
    fill_kernel<<<NB_edges, 256, 0, stream>>>(src, dst, cursor, ssrc, E);

    // ---- layer 1 ----
    agg_kernel<<<NB_agg, 256, 0, stream>>>(x, rowptr, ssrc, aggn, N);
    gemm2_kernel<true><<<NB_gemm, 256, 0, stream>>>(aggn, x, W_l1, W_r1, b1, h, N);

    // ---- layer 2 ----
    agg_kernel<<<NB_agg, 256, 0, stream>>>(h, rowptr, ssrc, aggn, N);
    gemm2_kernel<false><<<NB_gemm, 256, 0, stream>>>(aggn, h, W_l2, W_r2, b2, out, N);
}

// Round 2
// 157.936 us; speedup vs baseline: 2.2743x; 2.2743x over previous
//
#include <hip/hip_runtime.h>

#define D 128

typedef __attribute__((ext_vector_type(8))) short short8;
typedef __attribute__((ext_vector_type(4))) float f32x4;

typedef __attribute__((address_space(3))) unsigned int lds_u32_t;
typedef const __attribute__((address_space(1))) unsigned int glb_u32_t;

static __device__ __forceinline__ unsigned short f2bf(float f) {
    unsigned int u = __float_as_uint(f);
    unsigned int r = (u + 0x7fffu + ((u >> 16) & 1u)) >> 16;
    return (unsigned short)r;
}
static __device__ __forceinline__ float bf_lo(unsigned int u) {   // low 16 bits as bf16
    return __uint_as_float(u << 16);
}
static __device__ __forceinline__ float bf_hi(unsigned int u) {   // high 16 bits as bf16
    return __uint_as_float(u & 0xffff0000u);
}
static __device__ __forceinline__ unsigned int pack2(float lo, float hi) {
    return (unsigned int)f2bf(lo) | ((unsigned int)f2bf(hi) << 16);
}

// ---------------- CSR build ----------------

__global__ void count_deg_kernel(const int* __restrict__ dst, int* __restrict__ cnt, int E) {
    int e = blockIdx.x * 256 + threadIdx.x;
    if (e < E) atomicAdd(&cnt[dst[e]], 1);
}

__global__ void scan1_kernel(const int* __restrict__ cnt, int* __restrict__ rowptr,
                             int* __restrict__ bsum, int N) {
    __shared__ int tmp[256];
    int tid = threadIdx.x;
    int i = blockIdx.x * 256 + tid;
    int v = (i < N) ? cnt[i] : 0;
    tmp[tid] = v;
    __syncthreads();
    for (int off = 1; off < 256; off <<= 1) {
        int t = (tid >= off) ? tmp[tid - off] : 0;
        __syncthreads();
        tmp[tid] += t;
        __syncthreads();
    }
    if (i < N) rowptr[i] = tmp[tid] - v;
    if (tid == 255) bsum[blockIdx.x] = tmp[255];
}

__global__ void scan2_kernel(int* __restrict__ bsum, int NB) {
    __shared__ int tmp[256];
    int tid = threadIdx.x;
    int v = (tid < NB) ? bsum[tid] : 0;
    tmp[tid] = v;
    __syncthreads();
    for (int off = 1; off < 256; off <<= 1) {
        int t = (tid >= off) ? tmp[tid - off] : 0;
        __syncthreads();
        tmp[tid] += t;
        __syncthreads();
    }
    if (tid < NB) bsum[tid] = tmp[tid] - v;
}

__global__ void scan3_kernel(int* __restrict__ rowptr, const int* __restrict__ bsum,
                             int* __restrict__ cursor, int N, int E) {
    int i = blockIdx.x * 256 + threadIdx.x;
    if (i < N) {
        int v = rowptr[i] + bsum[blockIdx.x];
        rowptr[i] = v;
        cursor[i] = v;
    }
    if (i == 0) rowptr[N] = E;
}

__global__ void fill_kernel(const int* __restrict__ src, const int* __restrict__ dst,
                            int* __restrict__ cursor, int* __restrict__ ssrc, int E) {
    int e = blockIdx.x * 256 + threadIdx.x;
    if (e < E) {
        int d = dst[e];
        int pos = atomicAdd(&cursor[d], 1);
        ssrc[pos] = src[e];
    }
}

// ---------------- conversions ----------------

// x fp32 -> bf16, 8 elems/thread
__global__ void convert_x_kernel(const float* __restrict__ x, unsigned short* __restrict__ xb,
                                 int total8) {
    int i = blockIdx.x * 256 + threadIdx.x;
    if (i >= total8) return;
    const float4 v0 = *reinterpret_cast<const float4*>(x + (size_t)i * 8);
    const float4 v1 = *reinterpret_cast<const float4*>(x + (size_t)i * 8 + 4);
    uint4 o;
    o.x = pack2(v0.x, v0.y);
    o.y = pack2(v0.z, v0.w);
    o.z = pack2(v1.x, v1.y);
    o.w = pack2(v1.z, v1.w);
    *reinterpret_cast<uint4*>(xb + (size_t)i * 8) = o;
}

// W [128k][128n] fp32 -> Wt bf16 [n][chunk-swizzled k]:
//   elem index = m*16384 + n*128 + ((k>>3) ^ (n&15))*8 + (k&7)
__global__ void convert_w_kernel(const float* __restrict__ W0, const float* __restrict__ W1,
                                 const float* __restrict__ W2, const float* __restrict__ W3,
                                 unsigned short* __restrict__ wt) {
    int tid = blockIdx.x * 256 + threadIdx.x;     // 8192 threads total
    int m = tid >> 11;
    const float* W = (m == 0) ? W0 : (m == 1) ? W1 : (m == 2) ? W2 : W3;
    int r = tid & 2047;
    int n = r >> 4;
    int c = r & 15;                                // k-chunk 0..15 (8 k each)
    float f[8];
#pragma unroll
    for (int i = 0; i < 8; ++i) f[i] = W[(size_t)(c * 8 + i) * 128 + n];
    uint4 o;
    o.x = pack2(f[0], f[1]);
    o.y = pack2(f[2], f[3]);
    o.z = pack2(f[4], f[5]);
    o.w = pack2(f[6], f[7]);
    *reinterpret_cast<uint4*>(wt + (size_t)m * 16384 + n * 128 + (c ^ (n & 15)) * 8) = o;
}

// ---------------- mean aggregation (bf16 in, bf16 out, fp32 accum) ----------------
// one wave per node; quarter-waves process 4 edges concurrently; lane covers 8 feature elems

__global__ void agg_kernel(const unsigned short* __restrict__ feat, const int* __restrict__ rowptr,
                           const int* __restrict__ ssrc, unsigned short* __restrict__ out, int N) {
    int w = (blockIdx.x * blockDim.x + threadIdx.x) >> 6;
    if (w >= N) return;
    int lane = threadIdx.x & 63;
    int q = lane >> 4;
    int l15 = lane & 15;
    int beg = rowptr[w], end = rowptr[w + 1];
    float acc[8] = {0.f, 0.f, 0.f, 0.f, 0.f, 0.f, 0.f, 0.f};
    for (int e = beg + q; e < end; e += 4) {
        int s = ssrc[e];
        uint4 v = *reinterpret_cast<const uint4*>(feat + (size_t)s * D + l15 * 8);
        acc[0] += bf_lo(v.x); acc[1] += bf_hi(v.x);
        acc[2] += bf_lo(v.y); acc[3] += bf_hi(v.y);
        acc[4] += bf_lo(v.z); acc[5] += bf_hi(v.z);
        acc[6] += bf_lo(v.w); acc[7] += bf_hi(v.w);
    }
#pragma unroll
    for (int j = 0; j < 8; ++j) {
        acc[j] += __shfl_xor(acc[j], 16);
        acc[j] += __shfl_xor(acc[j], 32);
    }
    if (lane < 16) {
        int deg = end - beg;
        float inv = 1.0f / (float)(deg > 1 ? deg : 1);
        uint4 o;
        o.x = pack2(acc[0] * inv, acc[1] * inv);
        o.y = pack2(acc[2] * inv, acc[3] * inv);
        o.z = pack2(acc[4] * inv, acc[5] * inv);
        o.w = pack2(acc[6] * inv, acc[7] * inv);
        *reinterpret_cast<uint4*>(out + (size_t)w * D + l15 * 8) = o;
    }
}

// ---------------- MFMA dual-GEMM: out = A1*Wt[0] + A2*Wt[1] + bias [, relu] ----------------
// block: 256 thr / 4 waves; tile 128 rows x 128 cols; wave = 32 rows (M_rep=2) x 128 cols (N_rep=8)
// K = 2 passes x 128, staged in 32-k chunks.

template <bool RELU, bool OUT_BF16>
__global__ __launch_bounds__(256)
void gemm_mfma_kernel(const unsigned short* __restrict__ A1, const unsigned short* __restrict__ A2,
                      const unsigned short* __restrict__ Wt,   // [2][128n][128k-swz] bf16
                      const float* __restrict__ bias, void* __restrict__ outp, int N) {
    __shared__ unsigned short Wlds[128 * 128];   // 32 KB: current pass weights (swizzle baked in)
    __shared__ unsigned short Alds[128 * 32];    // 8 KB: A chunk, per-row chunk-rotated

    const int t = threadIdx.x;
    const int w = t >> 6;
    const int lane = t & 63;
    const int l15 = lane & 15;
    const int g = lane >> 4;
    const size_t row0 = (size_t)blockIdx.x * 128;

    f32x4 acc[2][8];
#pragma unroll
    for (int i = 0; i < 2; ++i)
#pragma unroll
        for (int j = 0; j < 8; ++j) acc[i][j] = (f32x4){0.f, 0.f, 0.f, 0.f};

    float bb[8];
#pragma unroll
    for (int j = 0; j < 8; ++j) bb[j] = bias[j * 16 + l15];

#pragma unroll
    for (int pass = 0; pass < 2; ++pass) {
        const unsigned short* __restrict__ A = pass ? A2 : A1;
        const unsigned short* __restrict__ Wp = Wt + (size_t)pass * 16384;
        // stage full 128x128 bf16 weight (linear copy; swizzle already in global layout)
#pragma unroll
        for (int i = 0; i < 8; ++i) {
            int d = t + 256 * i;
            __builtin_amdgcn_global_load_lds((glb_u32_t*)(Wp + (size_t)d * 8),
                                             (lds_u32_t*)(&Wlds[d * 8]), 16, 0, 0);
        }
#pragma unroll
        for (int kiter = 0; kiter < 4; ++kiter) {
            // stage A chunk: 128 rows x 32 k. LDS chunk d holds row r=d>>2, stored-slot cs=d&3,
            // logical k-chunk c = (cs - (r>>1)) & 3  (per-row rotation kills bank conflicts)
#pragma unroll
            for (int i = 0; i < 2; ++i) {
                int d = t + 256 * i;
                int r = d >> 2;
                int cs = d & 3;
                int c = (cs - (r >> 1)) & 3;
                const unsigned short* src = A + (row0 + r) * D + kiter * 32 + c * 8;
                __builtin_amdgcn_global_load_lds((glb_u32_t*)src,
                                                 (lds_u32_t*)(&Alds[d * 8]), 16, 0, 0);
            }
            __syncthreads();   // drains vmcnt -> A (and W) visible

            short8 a0, a1;
            {
                int r0 = w * 32 + l15;
                int cs0 = (g + (r0 >> 1)) & 3;
                a0 = *reinterpret_cast<const short8*>(&Alds[r0 * 32 + cs0 * 8]);
                int r1 = r0 + 16;
                int cs1 = (g + (r1 >> 1)) & 3;
                a1 = *reinterpret_cast<const short8*>(&Alds[r1 * 32 + cs1 * 8]);
            }
#pragma unroll
            for (int j = 0; j < 8; ++j) {
                int n = j * 16 + l15;
                int cs = (kiter * 4 + g) ^ l15;
                short8 b = *reinterpret_cast<const short8*>(&Wlds[n * 128 + cs * 8]);
                acc[0][j] = __builtin_amdgcn_mfma_f32_16x16x32_bf16(a0, b, acc[0][j], 0, 0, 0);
                acc[1][j] = __builtin_amdgcn_mfma_f32_16x16x32_bf16(a1, b, acc[1][j], 0, 0, 0);
            }
            __syncthreads();   // protect Alds/Wlds overwrite
        }
    }

    // epilogue: C/D layout col=lane&15, row=(lane>>4)*4+reg
    unsigned short* outb = (unsigned short*)outp;
    float* outf = (float*)outp;
#pragma unroll
    for (int i = 0; i < 2; ++i) {
        size_t rbase = row0 + w * 32 + i * 16 + g * 4;
#pragma unroll
        for (int reg = 0; reg < 4; ++reg) {
            size_t row = rbase + reg;
            if (row < (size_t)N) {
#pragma unroll
                for (int j = 0; j < 8; ++j) {
                    float v = acc[i][j][reg] + bb[j];
                    if (RELU) v = v > 0.f ? v : 0.f;
                    if (OUT_BF16) outb[row * D + j * 16 + l15] = f2bf(v);
                    else          outf[row * D + j * 16 + l15] = v;
                }
            }
        }
    }
}

// ---------------- launch ----------------

extern "C" void kernel_launch(void* const* d_in, const int* in_sizes, int n_in,
                              void* d_out, int out_size, void* d_ws, size_t ws_size,
                              hipStream_t stream) {
    const float* x    = (const float*)d_in[0];
    const int*   eidx = (const int*)d_in[1];
    const float* W_l1 = (const float*)d_in[2];
    const float* W_r1 = (const float*)d_in[3];
    const float* b1   = (const float*)d_in[4];
    const float* W_l2 = (const float*)d_in[5];
    const float* W_r2 = (const float*)d_in[6];
    const float* b2   = (const float*)d_in[7];
    float* out = (float*)d_out;

    const int N = in_sizes[0] / D;
    const int E = in_sizes[1] / 2;
    const int N_pad = (N + 127) & ~127;
    const int* src = eidx;
    const int* dst = eidx + E;

    char* ws = (char*)d_ws;
    size_t off = 0;
    auto alloc = [&](size_t bytes) {
        char* p = ws + off;
        off += (bytes + 511) & ~(size_t)511;
        return p;
    };
    int*            cnt    = (int*)alloc((size_t)N * 4);
    int*            rowptr = (int*)alloc((size_t)(N + 1) * 4);
    int*            cursor = (int*)alloc((size_t)N * 4);
    int*            bsum   = (int*)alloc(1024);
    int*            ssrc   = (int*)alloc((size_t)E * 4);
    unsigned short* xb     = (unsigned short*)alloc((size_t)N_pad * D * 2);
    unsigned short* hb     = (unsigned short*)alloc((size_t)N_pad * D * 2);
    unsigned short* aggb   = (unsigned short*)alloc((size_t)N_pad * D * 2);
    unsigned short* wt     = (unsigned short*)alloc((size_t)4 * 128 * 128 * 2);

    const int NB_edges = (E + 255) / 256;
    const int NB_nodes = (N + 255) / 256;
    const int NB_agg   = (N + 3) / 4;
    const int NB_gemm  = N_pad / 128;

    // conversions (independent of CSR)
    convert_x_kernel<<<(N * D / 8 + 255) / 256, 256, 0, stream>>>(x, xb, N * D / 8);
    convert_w_kernel<<<32, 256, 0, stream>>>(W_l1, W_r1, W_l2, W_r2, wt);

    // CSR build
    hipMemsetAsync(cnt, 0, (size_t)N * 4, stream);
    count_deg_kernel<<<NB_edges, 256, 0, stream>>>(dst, cnt, E);
    scan1_kernel<<<NB_nodes, 256, 0, stream>>>(cnt, rowptr, bsum, N);
    scan2_kernel<<<1, 256, 0, stream>>>(bsum, NB_nodes);
    scan3_kernel<<<NB_nodes, 256, 0, stream>>>(rowptr, bsum, cursor, N, E);
    fill_kernel<<<NB_edges, 256, 0, stream>>>(src, dst, cursor, ssrc, E);

    // layer 1
    agg_kernel<<<NB_agg, 256, 0, stream>>>(xb, rowptr, ssrc, aggb, N);
    gemm_mfma_kernel<true, true><<<NB_gemm, 256, 0, stream>>>(aggb, xb, wt, b1, hb, N);

    // layer 2
    agg_kernel<<<NB_agg, 256, 0, stream>>>(hb, rowptr, ssrc, aggb, N);
    gemm_mfma_kernel<false, false><<<NB_gemm, 256, 0, stream>>>(aggb, hb, wt + 2 * 16384, b2, out, N);
}